// Round 18
// baseline (185.937 us; speedup 1.0000x reference)
//
#include <hip/hip_runtime.h>
#include <hip/hip_bf16.h>

#define B_  2
#define T_  2048
#define C_  768
#define H_  12
#define HD_ 64

// scores are computed in exp2 domain: Q is pre-scaled by 0.125*log2(e)
#define QSCALE 0.18033688011f

typedef short bf16x8 __attribute__((ext_vector_type(8)));
typedef float f32x4  __attribute__((ext_vector_type(4)));
typedef unsigned short u16;
typedef unsigned int u32;

__device__ __forceinline__ u16 f2b(float f) {
  __hip_bfloat16 h = __float2bfloat16(f);
  return __builtin_bit_cast(u16, h);
}

// cheap round-half-up float->bf16 (no NaN handling; 2 VALU ops)
__device__ __forceinline__ u16 f2b_fast(float f) {
  u32 u = __builtin_bit_cast(u32, f);
  return (u16)((u + 0x8000u) >> 16);
}

// pack two floats to bf16 pair in one u32: 2 adds + 1 v_perm_b32
__device__ __forceinline__ u32 pack2(float a, float b) {
  u32 ua = __builtin_bit_cast(u32, a) + 0x8000u;
  u32 ub = __builtin_bit_cast(u32, b) + 0x8000u;
  return __builtin_amdgcn_perm(ub, ua, 0x07060302);
}

__device__ __forceinline__ void gload_lds16(const u16* g, u16* l) {
  __builtin_amdgcn_global_load_lds(
      (__attribute__((address_space(1))) void*)(void*)g,
      (__attribute__((address_space(3))) void*)(void*)l,
      16, 0, 0);
}

// ---------------- LayerNorm: fp32 in -> bf16 out ----------------
__global__ __launch_bounds__(256) void ln_kernel(const float* __restrict__ x,
                                                 const float* __restrict__ g,
                                                 const float* __restrict__ b,
                                                 u16* __restrict__ out) {
  int row = blockIdx.x;
  int tid = threadIdx.x;
  const float* xr = x + (size_t)row * C_;
  float v0 = xr[tid], v1 = xr[tid + 256], v2 = xr[tid + 512];
  float s = v0 + v1 + v2;
  float q = v0 * v0 + v1 * v1 + v2 * v2;
  for (int m = 1; m < 64; m <<= 1) {
    s += __shfl_xor(s, m, 64);
    q += __shfl_xor(q, m, 64);
  }
  __shared__ float red[8];
  int wv = tid >> 6, ln = tid & 63;
  if (ln == 0) { red[wv] = s; red[4 + wv] = q; }
  __syncthreads();
  s = red[0] + red[1] + red[2] + red[3];
  q = red[4] + red[5] + red[6] + red[7];
  float mu  = s * (1.0f / C_);
  float var = q * (1.0f / C_) - mu * mu;
  float rs  = rsqrtf(var + 1e-5f);
  u16* orow = out + (size_t)row * C_;
  orow[tid]       = f2b(g[tid]       * (v0 - mu) * rs + b[tid]);
  orow[tid + 256] = f2b(g[tid + 256] * (v1 - mu) * rs + b[tid + 256]);
  orow[tid + 512] = f2b(g[tid + 512] * (v2 - mu) * rs + b[tid + 512]);
}

// ------------- transpose+convert: fp32 W[K,N] -> bf16 Bt[N,K] -------------
__device__ __forceinline__ void tcvt_body(const float* __restrict__ W,
                                          u16* __restrict__ Bt,
                                          int Kd, int Nd, int bx, int by) {
  __shared__ u16 tile[32][33];
  int j0 = bx * 32, i0 = by * 32;
  int tx = threadIdx.x & 31, ty = threadIdx.x >> 5;  // ty 0..7
#pragma unroll
  for (int p = 0; p < 4; p++)
    tile[p * 8 + ty][tx] = f2b(W[(size_t)(i0 + p * 8 + ty) * Nd + j0 + tx]);
  __syncthreads();
#pragma unroll
  for (int p = 0; p < 4; p++)
    Bt[(size_t)(j0 + p * 8 + ty) * Kd + i0 + tx] = tile[tx][p * 8 + ty];
}

// all six weight transposes in ONE launch (flat 6912-block grid)
__global__ __launch_bounds__(256) void tcvt_all(const float* __restrict__ Wq,
                                                const float* __restrict__ Wk,
                                                const float* __restrict__ Wv,
                                                const float* __restrict__ Wo,
                                                const float* __restrict__ Wfc,
                                                const float* __restrict__ Wpr,
                                                u16* __restrict__ Oq,
                                                u16* __restrict__ Ok,
                                                u16* __restrict__ Ov,
                                                u16* __restrict__ Oo,
                                                u16* __restrict__ Ofc,
                                                u16* __restrict__ Opr) {
  int id = blockIdx.x;
  if (id < 2304) {                       // four 768x768, 576 tiles each
    int w = id / 576, idx = id - w * 576;
    const float* W = (w == 0) ? Wq : (w == 1) ? Wk : (w == 2) ? Wv : Wo;
    u16* O = (w == 0) ? Oq : (w == 1) ? Ok : (w == 2) ? Ov : Oo;
    tcvt_body(W, O, 768, 768, idx % 24, idx / 24);
  } else if (id < 4608) {                // W_fc [768,3072]
    int idx = id - 2304;
    tcvt_body(Wfc, Ofc, 768, 3072, idx % 96, idx / 96);
  } else {                               // W_proj [3072,768]
    int idx = id - 4608;
    tcvt_body(Wpr, Opr, 3072, 768, idx % 24, idx / 24);
  }
}

// ------------- GEMM: C[M,N] = A[M,K](bf16) * Bt[N,K]^T(bf16) -------------
// (MR*32) x (NR*32) tile, template BK, double-buffered LDS, ONE barrier per
// K-step. XOR-swizzled LDS (inverse-swizzled global source, swizzled reads).
// Swizzle: BK64 rows (128B): ch ^= row&7.  BK32 rows (64B): ch ^= (row>>1)&3.
// K = loop extent; lda = row stride of A and Bt (differs for split-K).
// MODE 1: fused QKV epilogue: q pre-scaled [B,H,T,64]; k [B,H,T,64];
//         v^T [B,H,64,T] with kv-within-64 permutation pi (for attn reg-P).
// MODE 3/5: fp32 acc+bias+resid   4: bf16 gelu(acc+bias)
// MODE 6: split-K partial, blockIdx.z = K-half; outF + z*M*N, raw fp32.
template <int MODE, int MR, int NR, int BK>
__global__ __launch_bounds__(256) void gemm_bt(const u16* __restrict__ A,
                                               const u16* __restrict__ Bt,
                                               int K, int lda, int N,
                                               u16* __restrict__ outB,
                                               float* __restrict__ outF,
                                               const float* __restrict__ bias,
                                               const float* __restrict__ resid) {
  constexpr int BM = MR * 32;
  constexpr int BN = NR * 32;
  constexpr int CH = BK / 8;       // 16B chunks per row
  constexpr int KK = BK / 32;      // K slices per step
  __shared__ u16 As[2][BM * BK];
  __shared__ u16 Bs[2][BN * BK];
  int tid = threadIdx.x;
  int wave = tid >> 6, lane = tid & 63;
  int wr = wave >> 1, wc = wave & 1;
  int laneQ = lane >> 4, laneM = lane & 15;
  int bm = blockIdx.x * BM, bn = blockIdx.y * BN;
  int zofs = (MODE == 6) ? blockIdx.z * K : 0;   // K-half offset (split-K)

  auto rsw = [](int row) {
    return (CH == 4) ? ((row >> 1) & 3) : (row & (CH - 1));
  };

  f32x4 zero = {0.f, 0.f, 0.f, 0.f};
  f32x4 acc[MR][NR];
#pragma unroll
  for (int m = 0; m < MR; m++)
#pragma unroll
    for (int n = 0; n < NR; n++) acc[m][n] = zero;

  auto stage = [&](int buf, int k0) {
#pragma unroll
    for (int i = 0; i < (BM * CH) / 256; i++) {
      int c = i * 256 + tid;
      int row = c / CH, sw = (c % CH) ^ rsw(row);
      gload_lds16(A + (size_t)(bm + row) * lda + zofs + k0 + (sw << 3),
                  &As[buf][(size_t)(i * 256 + wave * 64) * 8]);
    }
#pragma unroll
    for (int i = 0; i < (BN * CH) / 256; i++) {
      int c = i * 256 + tid;
      int row = c / CH, sw = (c % CH) ^ rsw(row);
      gload_lds16(Bt + (size_t)(bn + row) * lda + zofs + k0 + (sw << 3),
                  &Bs[buf][(size_t)(i * 256 + wave * 64) * 8]);
    }
  };

  auto compute = [&](int buf) {
    const u16* Ab = As[buf];
    const u16* Bb = Bs[buf];
#pragma unroll
    for (int kk = 0; kk < KK; kk++) {
      bf16x8 af[MR], bfr[NR];
#pragma unroll
      for (int m = 0; m < MR; m++) {
        int row = wr * (MR * 16) + m * 16 + laneM;
        int ch = (((kk << 2) | laneQ) & (CH - 1)) ^ rsw(row);
        af[m] = *(const bf16x8*)(Ab + row * BK + (ch << 3));
      }
#pragma unroll
      for (int n = 0; n < NR; n++) {
        int row = wc * (NR * 16) + n * 16 + laneM;
        int ch = (((kk << 2) | laneQ) & (CH - 1)) ^ rsw(row);
        bfr[n] = *(const bf16x8*)(Bb + row * BK + (ch << 3));
      }
      __builtin_amdgcn_s_setprio(1);
#pragma unroll
      for (int m = 0; m < MR; m++)
#pragma unroll
        for (int n = 0; n < NR; n++)
          acc[m][n] = __builtin_amdgcn_mfma_f32_16x16x32_bf16(af[m], bfr[n],
                                                              acc[m][n], 0, 0, 0);
      __builtin_amdgcn_s_setprio(0);
    }
  };

  int nk = K / BK;
  stage(0, 0);
  for (int t = 0; t < nk; ++t) {
    int cur = t & 1;
    __syncthreads();               // stage(t) landed in all waves
    if (t + 1 < nk) stage(cur ^ 1, (t + 1) * BK);
    compute(cur);
  }

  u16* kout  = outB + (size_t)4096 * 768;
  u16* vtout = outB + (size_t)2 * 4096 * 768;
  float* zoutF = (MODE == 6) ? outF + (size_t)blockIdx.z * 4096 * 768 : outF;
#pragma unroll
  for (int m = 0; m < MR; m++) {
#pragma unroll
    for (int n = 0; n < NR; n++) {
#pragma unroll
      for (int r = 0; r < 4; r++) {
        int row = bm + wr * (MR * 16) + m * 16 + laneQ * 4 + r;
        int col = bn + wc * NR * 16 + n * 16 + laneM;
        float v = acc[m][n][r];
        if (MODE == 1) {
          int b = row >> 11, t = row & 2047;
          int which = col / 768;
          int cc = col - which * 768;
          int h = cc >> 6, d = cc & 63;
          if (which == 0)
            outB[(((size_t)(b * H_ + h)) * T_ + t) * HD_ + d] = f2b(v * QSCALE);
          else if (which == 1)
            kout[(((size_t)(b * H_ + h)) * T_ + t) * HD_ + d] = f2b(v);
          else {
            // permute kv-within-64: kv=16*t4+4*Qb+rb -> k'=32*(t4>>1)+8*Qb+4*(t4&1)+rb
            int tt = t & 63;
            int t4 = tt >> 4, Qb = (tt >> 2) & 3, rb = tt & 3;
            int kp = ((t4 >> 1) << 5) | (Qb << 3) | ((t4 & 1) << 2) | rb;
            vtout[(((size_t)(b * H_ + h)) * HD_ + d) * T_ + (t & ~63) + kp] = f2b(v);
          }
        } else if (MODE == 3 || MODE == 5) {
          outF[(size_t)row * N + col] = v + bias[col] + resid[(size_t)row * N + col];
        } else if (MODE == 4) {
          float u = v + bias[col];
          outB[(size_t)row * N + col] = f2b(0.5f * u * (1.0f + erff(u * 0.70710678118f)));
        } else if (MODE == 6) {
          zoutF[(size_t)row * N + col] = v;
        }
      }
    }
  }
}

// ------------- split-K reduce: out = p0 + p1 + bias + resid -------------
__global__ __launch_bounds__(256) void redk_kernel(const float* __restrict__ p0,
                                                   const float* __restrict__ p1,
                                                   const float* __restrict__ bias,
                                                   const float* __restrict__ resid,
                                                   float* __restrict__ out) {
  const int n4 = 4096 * 768 / 4;
  for (int i = blockIdx.x * 256 + threadIdx.x; i < n4; i += gridDim.x * 256) {
    f32x4 a = ((const f32x4*)p0)[i];
    f32x4 b = ((const f32x4*)p1)[i];
    f32x4 r = ((const f32x4*)resid)[i];
    f32x4 bi = ((const f32x4*)bias)[i % 192];
    f32x4 o = a + b + r + bi;
    ((f32x4*)out)[i] = o;
  }
}

// ------------- flash attention: 2 waves x 32 q-rows, KVBLK=64 -------------
// Q (pre-scaled by 0.125*log2e), K: [B*H, T, 64] bf16. Vt: [B*H, 64, T] bf16
// with kv-within-64 permutation pi applied at the QKV epilogue.
// Swapped QK^T (mfma(K,Q)); MAX-FREE softmax; register-resident P.
// LDS-BW fix: each wave owns TWO 16-q subtiles (j=0,1) sharing the same
// K/V fragment loads -> LDS read bytes per unit work halved (was the
// binding constraint: 4 waves x 16KB/iter ~ 95 B/cy vs 85 ceiling).
// 128-thread blocks, 2-buffer LDS 32KB, 768-block snake LPT grid.
__global__ __launch_bounds__(128) void attn_kernel(const u16* __restrict__ Q,
                                                   const u16* __restrict__ K,
                                                   const u16* __restrict__ Vt,
                                                   u16* __restrict__ ctx) {
  __shared__ u16 Ks[2][4096];
  __shared__ u16 Vs[2][4096];

  int tid = threadIdx.x;
  int wave = tid >> 6, lane = tid & 63;
  int laneQ = lane >> 4, laneM = lane & 15;
  int id = blockIdx.x;
  int pass = id >> 8, slot = id & 255;
  int ii = pass * 256 + ((pass == 1) ? 255 - slot : slot);  // snake balance
  int bh = ii % 24;
  int bx = 31 - ii / 24;   // LPT: longest first
  int qW = bx * 64 + wave * 32;   // wave's first q row

  const u16* Qb = Q  + ((size_t)bh * T_ + qW) * HD_;
  const u16* Kb = K  + (size_t)bh * T_ * HD_;
  const u16* Vb = Vt + (size_t)bh * HD_ * T_;

  bf16x8 qf[2][2];
#pragma unroll
  for (int j = 0; j < 2; j++)
#pragma unroll
    for (int c = 0; c < 2; c++)
      qf[j][c] = *(const bf16x8*)(Qb + (size_t)(j * 16 + laneM) * HD_ + c * 32 + laneQ * 8);

  bf16x8 onesf;
#pragma unroll
  for (int i = 0; i < 8; i++) onesf[i] = (short)0x3F80;  // bf16 1.0

  f32x4 zero = {0.f, 0.f, 0.f, 0.f};
  f32x4 o[2][4];
  f32x4 ol[2];
#pragma unroll
  for (int j = 0; j < 2; j++) {
    ol[j] = zero;
#pragma unroll
    for (int g = 0; g < 4; g++) o[j][g] = zero;
  }

  // 8 x 16B loads per thread per tile (128 threads cover 2 x 8KB)
  auto stage = [&](int buf, int kb) {
    const u16* Kt = Kb + (size_t)kb * 64 * HD_;  // contiguous 64x64 tile
#pragma unroll
    for (int h = 0; h < 4; h++) {
      int c = h * 128 + tid;
      int row = c >> 3, c8 = c & 7;
      int sw = c8 ^ (row & 7);
      gload_lds16(Kt + (size_t)((row << 3) | sw) * 8,
                  &Ks[buf][(size_t)(h * 128 + wave * 64) * 8]);
      gload_lds16(Vb + (size_t)row * T_ + kb * 64 + (sw << 3),
                  &Vs[buf][(size_t)(h * 128 + wave * 64) * 8]);
    }
  };

  stage(0, 0);
  for (int kb = 0; kb <= bx; ++kb) {
    int cur = kb & 1;
    __syncthreads();  // staged 'cur' landed (vmcnt0) across all waves
    if (kb < bx) stage(cur ^ 1, kb + 1);
    const u16* Ksb = Ks[cur];
    const u16* Vsb = Vs[cur];

    // --- QK^T swapped: s[j][t][r] = score(kv=16t+4laneQ+r, q=j*16+laneM) ---
    f32x4 s[2][4];
#pragma unroll
    for (int j = 0; j < 2; j++)
#pragma unroll
      for (int t = 0; t < 4; t++) s[j][t] = zero;
    __builtin_amdgcn_s_setprio(1);
#pragma unroll
    for (int t = 0; t < 4; t++) {
      int krow = t * 16 + laneM;
#pragma unroll
      for (int c = 0; c < 2; c++) {
        bf16x8 kf = *(const bf16x8*)(Ksb + krow * 64 +
                                     ((((c << 2) | laneQ) ^ (krow & 7)) << 3));
        s[0][t] = __builtin_amdgcn_mfma_f32_16x16x32_bf16(kf, qf[0][c], s[0][t], 0, 0, 0);
        s[1][t] = __builtin_amdgcn_mfma_f32_16x16x32_bf16(kf, qf[1][c], s[1][t], 0, 0, 0);
      }
    }
    __builtin_amdgcn_s_setprio(0);

    // causal mask (diagonal tile only): exp2(-1e30) == 0
    if (kb == bx) {
#pragma unroll
      for (int j = 0; j < 2; j++) {
        int qrel = wave * 32 + j * 16 + laneM;
#pragma unroll
        for (int t = 0; t < 4; t++)
#pragma unroll
          for (int r = 0; r < 4; r++)
            if (16 * t + 4 * laneQ + r > qrel) s[j][t][r] = -1e30f;
      }
    }

    // --- P = exp2(s) directly (max-free), packed to bf16 in registers ---
    union { u32 u[4]; bf16x8 v; } P0[2], P1[2];
#pragma unroll
    for (int j = 0; j < 2; j++)
#pragma unroll
      for (int t = 0; t < 2; t++) {
        P0[j].u[2 * t]     = pack2(exp2f(s[j][t][0]), exp2f(s[j][t][1]));
        P0[j].u[2 * t + 1] = pack2(exp2f(s[j][t][2]), exp2f(s[j][t][3]));
        P1[j].u[2 * t]     = pack2(exp2f(s[j][t + 2][0]), exp2f(s[j][t + 2][1]));
        P1[j].u[2 * t + 1] = pack2(exp2f(s[j][t + 2][2]), exp2f(s[j][t + 2][3]));
      }

    // --- PV: o += P * V  (+ ones-column row-sums); V frags shared over j ---
    __builtin_amdgcn_s_setprio(1);
#pragma unroll
    for (int g = 0; g < 4; g++) {
      int d = g * 16 + laneM;
      bf16x8 v0 = *(const bf16x8*)(Vsb + d * 64 + ((laneQ ^ (d & 7)) << 3));
      bf16x8 v1 = *(const bf16x8*)(Vsb + d * 64 + (((4 | laneQ) ^ (d & 7)) << 3));
#pragma unroll
      for (int j = 0; j < 2; j++) {
        o[j][g] = __builtin_amdgcn_mfma_f32_16x16x32_bf16(P0[j].v, v0, o[j][g], 0, 0, 0);
        o[j][g] = __builtin_amdgcn_mfma_f32_16x16x32_bf16(P1[j].v, v1, o[j][g], 0, 0, 0);
      }
    }
#pragma unroll
    for (int j = 0; j < 2; j++) {
      ol[j] = __builtin_amdgcn_mfma_f32_16x16x32_bf16(P0[j].v, onesf, ol[j], 0, 0, 0);
      ol[j] = __builtin_amdgcn_mfma_f32_16x16x32_bf16(P1[j].v, onesf, ol[j], 0, 0, 0);
    }
    __builtin_amdgcn_s_setprio(0);
  }

  int b = bh / H_, h = bh % H_;
#pragma unroll
  for (int j = 0; j < 2; j++)
#pragma unroll
    for (int r = 0; r < 4; r++) {
      int t = qW + j * 16 + laneQ * 4 + r;
      float inv = 1.0f / ol[j][r];
      size_t base = ((size_t)(b * T_ + t)) * C_ + h * HD_;
#pragma unroll
      for (int g = 0; g < 4; g++)
        ctx[base + g * 16 + laneM] = f2b_fast(o[j][g][r] * inv);
    }
}

// ---------------------------------------------------------------
extern "C" void kernel_launch(void* const* d_in, const int* in_sizes, int n_in,
                              void* d_out, int out_size, void* d_ws, size_t ws_size,
                              hipStream_t stream) {
  const float* x      = (const float*)d_in[0];
  const float* Wq     = (const float*)d_in[1];
  const float* Wk     = (const float*)d_in[2];
  const float* Wv     = (const float*)d_in[3];
  const float* Wo     = (const float*)d_in[4];
  const float* bo     = (const float*)d_in[5];
  const float* W_fc   = (const float*)d_in[6];
  const float* b_fc   = (const float*)d_in[7];
  const float* W_proj = (const float*)d_in[8];
  const float* b_proj = (const float*)d_in[9];
  const float* g1     = (const float*)d_in[10];
  const float* be1    = (const float*)d_in[11];
  const float* g2     = (const float*)d_in[12];
  const float* be2    = (const float*)d_in[13];
  float* out = (float*)d_out;

  char* ws = (char*)d_ws;
  size_t off = 0;
  auto alloc = [&](size_t bytes) {
    size_t o = off;
    off += (bytes + 255) & ~(size_t)255;
    return o;
  };
  u16*   xn    = (u16*)(ws + alloc((size_t)4096 * 768 * 2));
  u16*   xn2   = (u16*)(ws + alloc((size_t)4096 * 768 * 2));
  u16*   qkv   = (u16*)(ws + alloc((size_t)3 * 4096 * 768 * 2));
  u16*   ctx   = (u16*)(ws + alloc((size_t)4096 * 768 * 2));
  float* xa    = (float*)(ws + alloc((size_t)4096 * 768 * 4));
  u16*   hbuf  = (u16*)(ws + alloc((size_t)4096 * 3072 * 2));
  u16*   wqkvT = (u16*)(ws + alloc((size_t)2304 * 768 * 2));
  u16*   woT   = (u16*)(ws + alloc((size_t)768 * 768 * 2));
  u16*   wfcT  = (u16*)(ws + alloc((size_t)768 * 3072 * 2));
  u16*   wprT  = (u16*)(ws + alloc((size_t)3072 * 768 * 2));

  u16* q  = qkv;
  u16* k  = qkv + (size_t)4096 * 768;
  u16* vt = qkv + (size_t)2 * 4096 * 768;
  // split-K partials: p0 spans xn+xn2 (two contiguous 6.29MB allocs =
  // exactly 4096*768*4 B); p1 = pK + 4096*768 floats = start of qkv.
  float* pK = (float*)xn;

  // LN1 + all weight converts (one launch)
  ln_kernel<<<4096, 256, 0, stream>>>(x, g1, be1, xn);
  tcvt_all<<<6912, 256, 0, stream>>>(
      Wq, Wk, Wv, Wo, W_fc, W_proj,
      wqkvT, wqkvT + (size_t)768 * 768, wqkvT + (size_t)2 * 768 * 768,
      woT, wfcT, wprT);

  // fused QKV projection: [4096,768] @ [768,2304]  (128x128, BK32)
  gemm_bt<1, 4, 4, 32><<<dim3(32, 18), 256, 0, stream>>>(xn, wqkvT, 768, 768, 2304, qkv, nullptr, nullptr, nullptr);

  // causal flash attention -> ctx [B,T,C]
  attn_kernel<<<768, 128, 0, stream>>>(q, k, vt, ctx);

  // x_a = ctx @ Wo + bo + x   (fp32, 128x64 BK64 dbuf, 384 blocks)
  gemm_bt<3, 4, 2, 64><<<dim3(32, 12), 256, 0, stream>>>(ctx, woT, 768, 768, 768, nullptr, xa, bo, x);

  // LN2 (xn2 is part of p0, but p0 is only written by the proj GEMM which
  // runs after FC consumed xn2 -- safe)
  ln_kernel<<<4096, 256, 0, stream>>>(xa, g2, be2, xn2);

  // h = gelu(xn2 @ W_fc + b_fc)   (bf16, 128x128 BK32)
  gemm_bt<4, 4, 4, 32><<<dim3(32, 24), 256, 0, stream>>>(xn2, wfcT, 768, 768, 3072, hbuf, nullptr, b_fc, nullptr);

  // proj split-K=2: z=0 -> pK, z=1 -> pK + 4096*768 (= qkv region)
  gemm_bt<6, 4, 2, 64><<<dim3(32, 12, 2), 256, 0, stream>>>(hbuf, wprT, 1536, 3072, 768, nullptr, pK, nullptr, nullptr);

  // out = p0 + p1 + b_proj + xa
  redk_kernel<<<1024, 256, 0, stream>>>(pK, pK + (size_t)4096 * 768, b_proj, xa, out);
}

// Round 19
// 169.944 us; speedup vs baseline: 1.0941x; 1.0941x over previous
//
#include <hip/hip_runtime.h>
#include <hip/hip_bf16.h>

#define B_  2
#define T_  2048
#define C_  768
#define H_  12
#define HD_ 64

// scores are computed in exp2 domain: Q is pre-scaled by 0.125*log2(e)
#define QSCALE 0.18033688011f

typedef short bf16x8 __attribute__((ext_vector_type(8)));
typedef float f32x4  __attribute__((ext_vector_type(4)));
typedef unsigned short u16;
typedef unsigned int u32;

__device__ __forceinline__ u16 f2b(float f) {
  __hip_bfloat16 h = __float2bfloat16(f);
  return __builtin_bit_cast(u16, h);
}

// cheap round-half-up float->bf16 (no NaN handling; 2 VALU ops)
__device__ __forceinline__ u16 f2b_fast(float f) {
  u32 u = __builtin_bit_cast(u32, f);
  return (u16)((u + 0x8000u) >> 16);
}

// pack two floats to bf16 pair in one u32: 2 adds + 1 v_perm_b32
__device__ __forceinline__ u32 pack2(float a, float b) {
  u32 ua = __builtin_bit_cast(u32, a) + 0x8000u;
  u32 ub = __builtin_bit_cast(u32, b) + 0x8000u;
  return __builtin_amdgcn_perm(ub, ua, 0x07060302);
}

__device__ __forceinline__ void gload_lds16(const u16* g, u16* l) {
  __builtin_amdgcn_global_load_lds(
      (__attribute__((address_space(1))) void*)(void*)g,
      (__attribute__((address_space(3))) void*)(void*)l,
      16, 0, 0);
}

// ---------------- LayerNorm: fp32 in -> bf16 out ----------------
__global__ __launch_bounds__(256) void ln_kernel(const float* __restrict__ x,
                                                 const float* __restrict__ g,
                                                 const float* __restrict__ b,
                                                 u16* __restrict__ out) {
  int row = blockIdx.x;
  int tid = threadIdx.x;
  const float* xr = x + (size_t)row * C_;
  float v0 = xr[tid], v1 = xr[tid + 256], v2 = xr[tid + 512];
  float s = v0 + v1 + v2;
  float q = v0 * v0 + v1 * v1 + v2 * v2;
  for (int m = 1; m < 64; m <<= 1) {
    s += __shfl_xor(s, m, 64);
    q += __shfl_xor(q, m, 64);
  }
  __shared__ float red[8];
  int wv = tid >> 6, ln = tid & 63;
  if (ln == 0) { red[wv] = s; red[4 + wv] = q; }
  __syncthreads();
  s = red[0] + red[1] + red[2] + red[3];
  q = red[4] + red[5] + red[6] + red[7];
  float mu  = s * (1.0f / C_);
  float var = q * (1.0f / C_) - mu * mu;
  float rs  = rsqrtf(var + 1e-5f);
  u16* orow = out + (size_t)row * C_;
  orow[tid]       = f2b(g[tid]       * (v0 - mu) * rs + b[tid]);
  orow[tid + 256] = f2b(g[tid + 256] * (v1 - mu) * rs + b[tid + 256]);
  orow[tid + 512] = f2b(g[tid + 512] * (v2 - mu) * rs + b[tid + 512]);
}

// ------------- transpose+convert: fp32 W[K,N] -> bf16 Bt[N,K] -------------
__device__ __forceinline__ void tcvt_body(const float* __restrict__ W,
                                          u16* __restrict__ Bt,
                                          int Kd, int Nd, int bx, int by) {
  __shared__ u16 tile[32][33];
  int j0 = bx * 32, i0 = by * 32;
  int tx = threadIdx.x & 31, ty = threadIdx.x >> 5;  // ty 0..7
#pragma unroll
  for (int p = 0; p < 4; p++)
    tile[p * 8 + ty][tx] = f2b(W[(size_t)(i0 + p * 8 + ty) * Nd + j0 + tx]);
  __syncthreads();
#pragma unroll
  for (int p = 0; p < 4; p++)
    Bt[(size_t)(j0 + p * 8 + ty) * Kd + i0 + tx] = tile[tx][p * 8 + ty];
}

// all six weight transposes in ONE launch (flat 6912-block grid)
__global__ __launch_bounds__(256) void tcvt_all(const float* __restrict__ Wq,
                                                const float* __restrict__ Wk,
                                                const float* __restrict__ Wv,
                                                const float* __restrict__ Wo,
                                                const float* __restrict__ Wfc,
                                                const float* __restrict__ Wpr,
                                                u16* __restrict__ Oq,
                                                u16* __restrict__ Ok,
                                                u16* __restrict__ Ov,
                                                u16* __restrict__ Oo,
                                                u16* __restrict__ Ofc,
                                                u16* __restrict__ Opr) {
  int id = blockIdx.x;
  if (id < 2304) {                       // four 768x768, 576 tiles each
    int w = id / 576, idx = id - w * 576;
    const float* W = (w == 0) ? Wq : (w == 1) ? Wk : (w == 2) ? Wv : Wo;
    u16* O = (w == 0) ? Oq : (w == 1) ? Ok : (w == 2) ? Ov : Oo;
    tcvt_body(W, O, 768, 768, idx % 24, idx / 24);
  } else if (id < 4608) {                // W_fc [768,3072]
    int idx = id - 2304;
    tcvt_body(Wfc, Ofc, 768, 3072, idx % 96, idx / 96);
  } else {                               // W_proj [3072,768]
    int idx = id - 4608;
    tcvt_body(Wpr, Opr, 3072, 768, idx % 24, idx / 24);
  }
}

// ------------- GEMM: C[M,N] = A[M,K](bf16) * Bt[N,K]^T(bf16) -------------
// (MR*32) x (NR*32) tile, template BK, double-buffered LDS, ONE barrier per
// K-step. XOR-swizzled LDS (inverse-swizzled global source, swizzled reads).
// Swizzle: BK64 rows (128B): ch ^= row&7.  BK32 rows (64B): ch ^= (row>>1)&3.
// K = loop extent; lda = row stride of A and Bt (differs for split-K).
// MODE 1: fused QKV epilogue: q pre-scaled [B,H,T,64]; k [B,H,T,64];
//         v^T [B,H,64,T] with kv-within-64 permutation pi (for attn reg-P).
// MODE 3/5: fp32 acc+bias+resid   4: bf16 gelu(acc+bias)
// MODE 6: split-K partial, blockIdx.z = K-half; outF + z*M*N, raw fp32.
template <int MODE, int MR, int NR, int BK>
__global__ __launch_bounds__(256) void gemm_bt(const u16* __restrict__ A,
                                               const u16* __restrict__ Bt,
                                               int K, int lda, int N,
                                               u16* __restrict__ outB,
                                               float* __restrict__ outF,
                                               const float* __restrict__ bias,
                                               const float* __restrict__ resid) {
  constexpr int BM = MR * 32;
  constexpr int BN = NR * 32;
  constexpr int CH = BK / 8;       // 16B chunks per row
  constexpr int KK = BK / 32;      // K slices per step
  __shared__ u16 As[2][BM * BK];
  __shared__ u16 Bs[2][BN * BK];
  int tid = threadIdx.x;
  int wave = tid >> 6, lane = tid & 63;
  int wr = wave >> 1, wc = wave & 1;
  int laneQ = lane >> 4, laneM = lane & 15;
  int bm = blockIdx.x * BM, bn = blockIdx.y * BN;
  int zofs = (MODE == 6) ? blockIdx.z * K : 0;   // K-half offset (split-K)

  auto rsw = [](int row) {
    return (CH == 4) ? ((row >> 1) & 3) : (row & (CH - 1));
  };

  f32x4 zero = {0.f, 0.f, 0.f, 0.f};
  f32x4 acc[MR][NR];
#pragma unroll
  for (int m = 0; m < MR; m++)
#pragma unroll
    for (int n = 0; n < NR; n++) acc[m][n] = zero;

  auto stage = [&](int buf, int k0) {
#pragma unroll
    for (int i = 0; i < (BM * CH) / 256; i++) {
      int c = i * 256 + tid;
      int row = c / CH, sw = (c % CH) ^ rsw(row);
      gload_lds16(A + (size_t)(bm + row) * lda + zofs + k0 + (sw << 3),
                  &As[buf][(size_t)(i * 256 + wave * 64) * 8]);
    }
#pragma unroll
    for (int i = 0; i < (BN * CH) / 256; i++) {
      int c = i * 256 + tid;
      int row = c / CH, sw = (c % CH) ^ rsw(row);
      gload_lds16(Bt + (size_t)(bn + row) * lda + zofs + k0 + (sw << 3),
                  &Bs[buf][(size_t)(i * 256 + wave * 64) * 8]);
    }
  };

  auto compute = [&](int buf) {
    const u16* Ab = As[buf];
    const u16* Bb = Bs[buf];
#pragma unroll
    for (int kk = 0; kk < KK; kk++) {
      bf16x8 af[MR], bfr[NR];
#pragma unroll
      for (int m = 0; m < MR; m++) {
        int row = wr * (MR * 16) + m * 16 + laneM;
        int ch = (((kk << 2) | laneQ) & (CH - 1)) ^ rsw(row);
        af[m] = *(const bf16x8*)(Ab + row * BK + (ch << 3));
      }
#pragma unroll
      for (int n = 0; n < NR; n++) {
        int row = wc * (NR * 16) + n * 16 + laneM;
        int ch = (((kk << 2) | laneQ) & (CH - 1)) ^ rsw(row);
        bfr[n] = *(const bf16x8*)(Bb + row * BK + (ch << 3));
      }
      __builtin_amdgcn_s_setprio(1);
#pragma unroll
      for (int m = 0; m < MR; m++)
#pragma unroll
        for (int n = 0; n < NR; n++)
          acc[m][n] = __builtin_amdgcn_mfma_f32_16x16x32_bf16(af[m], bfr[n],
                                                              acc[m][n], 0, 0, 0);
      __builtin_amdgcn_s_setprio(0);
    }
  };

  int nk = K / BK;
  stage(0, 0);
  for (int t = 0; t < nk; ++t) {
    int cur = t & 1;
    __syncthreads();               // stage(t) landed in all waves
    if (t + 1 < nk) stage(cur ^ 1, (t + 1) * BK);
    compute(cur);
  }

  u16* kout  = outB + (size_t)4096 * 768;
  u16* vtout = outB + (size_t)2 * 4096 * 768;
  float* zoutF = (MODE == 6) ? outF + (size_t)blockIdx.z * 4096 * 768 : outF;
#pragma unroll
  for (int m = 0; m < MR; m++) {
#pragma unroll
    for (int n = 0; n < NR; n++) {
#pragma unroll
      for (int r = 0; r < 4; r++) {
        int row = bm + wr * (MR * 16) + m * 16 + laneQ * 4 + r;
        int col = bn + wc * NR * 16 + n * 16 + laneM;
        float v = acc[m][n][r];
        if (MODE == 1) {
          int b = row >> 11, t = row & 2047;
          int which = col / 768;
          int cc = col - which * 768;
          int h = cc >> 6, d = cc & 63;
          if (which == 0)
            outB[(((size_t)(b * H_ + h)) * T_ + t) * HD_ + d] = f2b(v * QSCALE);
          else if (which == 1)
            kout[(((size_t)(b * H_ + h)) * T_ + t) * HD_ + d] = f2b(v);
          else {
            // permute kv-within-64: kv=16*t4+4*Qb+rb -> k'=32*(t4>>1)+8*Qb+4*(t4&1)+rb
            int tt = t & 63;
            int t4 = tt >> 4, Qb = (tt >> 2) & 3, rb = tt & 3;
            int kp = ((t4 >> 1) << 5) | (Qb << 3) | ((t4 & 1) << 2) | rb;
            vtout[(((size_t)(b * H_ + h)) * HD_ + d) * T_ + (t & ~63) + kp] = f2b(v);
          }
        } else if (MODE == 3 || MODE == 5) {
          outF[(size_t)row * N + col] = v + bias[col] + resid[(size_t)row * N + col];
        } else if (MODE == 4) {
          float u = v + bias[col];
          outB[(size_t)row * N + col] = f2b(0.5f * u * (1.0f + erff(u * 0.70710678118f)));
        } else if (MODE == 6) {
          zoutF[(size_t)row * N + col] = v;
        }
      }
    }
  }
}

// ------------- split-K reduce: out = p0 + p1 + bias + resid -------------
__global__ __launch_bounds__(256) void redk_kernel(const float* __restrict__ p0,
                                                   const float* __restrict__ p1,
                                                   const float* __restrict__ bias,
                                                   const float* __restrict__ resid,
                                                   float* __restrict__ out) {
  const int n4 = 4096 * 768 / 4;
  for (int i = blockIdx.x * 256 + threadIdx.x; i < n4; i += gridDim.x * 256) {
    f32x4 a = ((const f32x4*)p0)[i];
    f32x4 b = ((const f32x4*)p1)[i];
    f32x4 r = ((const f32x4*)resid)[i];
    f32x4 bi = ((const f32x4*)bias)[i % 192];
    f32x4 o = a + b + r + bi;
    ((f32x4*)out)[i] = o;
  }
}

// ------- flash attention, split-KV x2, register-resident P, KVBLK=64 ------
// Q (pre-scaled by 0.125*log2e), K: [B*H, T, 64] bf16. Vt: [B*H, 64, T] bf16
// with kv-within-64 permutation pi applied at the QKV epilogue.
// Swapped QK^T (mfma(K,Q)); MAX-FREE softmax (implicit max 0 shared by all
// parts -> partial o/ol over disjoint kv ranges combine by ADDITION).
// Grid 1536: id = (ii<<1)|z; part z covers kv tiles [z?ks:0, z?n:ks), where
// n = bx+1, ks = (n+1)/2. Partials: po[z][B,T,C] fp32, olp[z][bh][T].
// 4 waves x 16 q-rows; 2-buffer LDS 32KB -> 5 blocks/CU (occupancy fix:
// grid was 768 = 3 blocks/CU, capping latency hiding; now 20 waves/CU).
__global__ __launch_bounds__(256) void attn_kernel(const u16* __restrict__ Q,
                                                   const u16* __restrict__ K,
                                                   const u16* __restrict__ Vt,
                                                   float* __restrict__ po,
                                                   float* __restrict__ olp) {
  __shared__ u16 Ks[2][4096];
  __shared__ u16 Vs[2][4096];

  int tid = threadIdx.x;
  int wave = tid >> 6, lane = tid & 63;
  int laneQ = lane >> 4, laneM = lane & 15;
  int id = blockIdx.x;
  int ii = id >> 1, z = id & 1;
  int bh = ii % 24;
  int bx = 31 - ii / 24;          // LPT: longest parts first
  int n  = bx + 1;
  int ks = (n + 1) >> 1;
  int kb0  = z ? ks : 0;
  int kEnd = z ? n  : ks;
  int q0 = bx * 64 + wave * 16;
  int qrel = wave * 16 + laneM;   // causal threshold within the diagonal tile

  const u16* Qb = Q  + ((size_t)bh * T_ + q0) * HD_;
  const u16* Kb = K  + (size_t)bh * T_ * HD_;
  const u16* Vb = Vt + (size_t)bh * HD_ * T_;

  bf16x8 qf[2];
  qf[0] = *(const bf16x8*)(Qb + laneM * HD_ + laneQ * 8);
  qf[1] = *(const bf16x8*)(Qb + laneM * HD_ + 32 + laneQ * 8);

  bf16x8 onesf;
#pragma unroll
  for (int i = 0; i < 8; i++) onesf[i] = (short)0x3F80;  // bf16 1.0

  f32x4 zero = {0.f, 0.f, 0.f, 0.f};
  f32x4 o[4];
  f32x4 ol = zero;                 // row-sums (D-layout, q = 4*laneQ+r)
#pragma unroll
  for (int g = 0; g < 4; g++) o[g] = zero;

  auto stage = [&](int buf, int kb) {
    const u16* Kt = Kb + (size_t)kb * 64 * HD_;  // contiguous 64x64 tile
#pragma unroll
    for (int h = 0; h < 2; h++) {
      int c = h * 256 + wave * 64 + lane;
      int row = c >> 3, c8 = c & 7;
      int sw = c8 ^ (row & 7);
      gload_lds16(Kt + (size_t)((row << 3) | sw) * 8,
                  &Ks[buf][(size_t)(h * 256 + wave * 64) * 8]);
      gload_lds16(Vb + (size_t)row * T_ + kb * 64 + (sw << 3),
                  &Vs[buf][(size_t)(h * 256 + wave * 64) * 8]);
    }
  };

  if (kb0 < kEnd) stage(0, kb0);
  for (int kb = kb0; kb < kEnd; ++kb) {
    int cur = (kb - kb0) & 1;
    __syncthreads();  // staged 'cur' landed (vmcnt0) across all waves
    if (kb + 1 < kEnd) stage(cur ^ 1, kb + 1);
    const u16* Ksb = Ks[cur];
    const u16* Vsb = Vs[cur];

    // --- QK^T swapped: s[t][r] = score(kv = 16t+4laneQ+r, q = laneM) ---
    f32x4 s[4];
#pragma unroll
    for (int t = 0; t < 4; t++) s[t] = zero;
    __builtin_amdgcn_s_setprio(1);
#pragma unroll
    for (int t = 0; t < 4; t++) {
      int krow = t * 16 + laneM;
#pragma unroll
      for (int c = 0; c < 2; c++) {
        bf16x8 kf = *(const bf16x8*)(Ksb + krow * 64 +
                                     ((((c << 2) | laneQ) ^ (krow & 7)) << 3));
        s[t] = __builtin_amdgcn_mfma_f32_16x16x32_bf16(kf, qf[c], s[t], 0, 0, 0);
      }
    }
    __builtin_amdgcn_s_setprio(0);

    // causal mask (diagonal tile only): exp2(-1e30) == 0
    if (kb == bx) {
#pragma unroll
      for (int t = 0; t < 4; t++)
#pragma unroll
        for (int r = 0; r < 4; r++)
          if (16 * t + 4 * laneQ + r > qrel) s[t][r] = -1e30f;
    }

    // --- P = exp2(s) directly (max-free), packed to bf16 in registers ---
    union { u32 u[4]; bf16x8 v; } P0, P1;
#pragma unroll
    for (int t = 0; t < 2; t++) {
      P0.u[2 * t]     = pack2(exp2f(s[t][0]), exp2f(s[t][1]));
      P0.u[2 * t + 1] = pack2(exp2f(s[t][2]), exp2f(s[t][3]));
      P1.u[2 * t]     = pack2(exp2f(s[t + 2][0]), exp2f(s[t + 2][1]));
      P1.u[2 * t + 1] = pack2(exp2f(s[t + 2][2]), exp2f(s[t + 2][3]));
    }

    // --- PV: o += P * V  (+ ones-column row-sum) ---
    __builtin_amdgcn_s_setprio(1);
#pragma unroll
    for (int g = 0; g < 4; g++) {
      int d = g * 16 + laneM;
      bf16x8 v0 = *(const bf16x8*)(Vsb + d * 64 + ((laneQ ^ (d & 7)) << 3));
      bf16x8 v1 = *(const bf16x8*)(Vsb + d * 64 + (((4 | laneQ) ^ (d & 7)) << 3));
      o[g] = __builtin_amdgcn_mfma_f32_16x16x32_bf16(P0.v, v0, o[g], 0, 0, 0);
      o[g] = __builtin_amdgcn_mfma_f32_16x16x32_bf16(P1.v, v1, o[g], 0, 0, 0);
    }
    ol = __builtin_amdgcn_mfma_f32_16x16x32_bf16(P0.v, onesf, ol, 0, 0, 0);
    ol = __builtin_amdgcn_mfma_f32_16x16x32_bf16(P1.v, onesf, ol, 0, 0, 0);
    __builtin_amdgcn_s_setprio(0);
  }

  // write fp32 partials (empty parts write zeros)
  int b = bh / H_, h = bh % H_;
  float* poz = po + (size_t)z * 4096 * 768;
#pragma unroll
  for (int r = 0; r < 4; r++) {
    int t = q0 + laneQ * 4 + r;
    size_t base = ((size_t)(b * T_ + t)) * C_ + h * HD_;
#pragma unroll
    for (int g = 0; g < 4; g++)
      poz[base + g * 16 + laneM] = o[g][r];
    if (laneM == 0)
      olp[(size_t)(z * 24 + bh) * T_ + t] = ol[r];
  }
}

// ------- combine: ctx = (o0+o1) / (ol0+ol1), bf16 out -------
__global__ __launch_bounds__(256) void attn_combine(const float* __restrict__ po,
                                                    const float* __restrict__ olp,
                                                    u16* __restrict__ ctx) {
  int i = blockIdx.x * 256 + threadIdx.x;   // [0, 4096*768/4)
  const f32x4* p0 = (const f32x4*)po;
  const f32x4* p1 = (const f32x4*)(po + (size_t)4096 * 768);
  f32x4 a = p0[i], c4 = p1[i];
  int idx = i << 2;
  int row = idx / 768;
  int cc = idx - row * 768;
  int h = cc >> 6;
  int b = row >> 11, t = row & 2047;
  int bh = b * H_ + h;
  float l = olp[(size_t)bh * T_ + t] + olp[(size_t)(24 + bh) * T_ + t];
  float inv = 1.0f / l;
  u32 lo = pack2((a[0] + c4[0]) * inv, (a[1] + c4[1]) * inv);
  u32 hi = pack2((a[2] + c4[2]) * inv, (a[3] + c4[3]) * inv);
  u32* dst = (u32*)(ctx + (size_t)idx);
  dst[0] = lo;
  dst[1] = hi;
}

// ---------------------------------------------------------------
extern "C" void kernel_launch(void* const* d_in, const int* in_sizes, int n_in,
                              void* d_out, int out_size, void* d_ws, size_t ws_size,
                              hipStream_t stream) {
  const float* x      = (const float*)d_in[0];
  const float* Wq     = (const float*)d_in[1];
  const float* Wk     = (const float*)d_in[2];
  const float* Wv     = (const float*)d_in[3];
  const float* Wo     = (const float*)d_in[4];
  const float* bo     = (const float*)d_in[5];
  const float* W_fc   = (const float*)d_in[6];
  const float* b_fc   = (const float*)d_in[7];
  const float* W_proj = (const float*)d_in[8];
  const float* b_proj = (const float*)d_in[9];
  const float* g1     = (const float*)d_in[10];
  const float* be1    = (const float*)d_in[11];
  const float* g2     = (const float*)d_in[12];
  const float* be2    = (const float*)d_in[13];
  float* out = (float*)d_out;

  char* ws = (char*)d_ws;
  size_t off = 0;
  auto alloc = [&](size_t bytes) {
    size_t o = off;
    off += (bytes + 255) & ~(size_t)255;
    return o;
  };
  u16*   xn    = (u16*)(ws + alloc((size_t)4096 * 768 * 2));
  u16*   xn2   = (u16*)(ws + alloc((size_t)4096 * 768 * 2));
  u16*   qkv   = (u16*)(ws + alloc((size_t)3 * 4096 * 768 * 2));
  u16*   ctx   = (u16*)(ws + alloc((size_t)4096 * 768 * 2));
  float* xa    = (float*)(ws + alloc((size_t)4096 * 768 * 4));
  u16*   hbuf  = (u16*)(ws + alloc((size_t)4096 * 3072 * 2));
  u16*   wqkvT = (u16*)(ws + alloc((size_t)2304 * 768 * 2));
  u16*   woT   = (u16*)(ws + alloc((size_t)768 * 768 * 2));
  u16*   wfcT  = (u16*)(ws + alloc((size_t)768 * 3072 * 2));
  u16*   wprT  = (u16*)(ws + alloc((size_t)3072 * 768 * 2));

  u16* q  = qkv;
  u16* k  = qkv + (size_t)4096 * 768;
  u16* vt = qkv + (size_t)2 * 4096 * 768;
  // split-K partials: p0 spans xn+xn2 (two contiguous 6.29MB allocs =
  // exactly 4096*768*4 B); p1 = pK + 4096*768 floats = start of qkv.
  float* pK = (float*)xn;
  // attn split-KV partials: po = hbuf region (2 x [4096][768] fp32 =
  // exactly 4096*3072*2 B); olp = xn2 region (2 x 24 x 2048 fp32 = 384KB).
  // Both consumed by attn_combine before their next writers (FC / LN2).
  float* po  = (float*)hbuf;
  float* olp = (float*)xn2;

  // LN1 + all weight converts (one launch)
  ln_kernel<<<4096, 256, 0, stream>>>(x, g1, be1, xn);
  tcvt_all<<<6912, 256, 0, stream>>>(
      Wq, Wk, Wv, Wo, W_fc, W_proj,
      wqkvT, wqkvT + (size_t)768 * 768, wqkvT + (size_t)2 * 768 * 768,
      woT, wfcT, wprT);

  // fused QKV projection: [4096,768] @ [768,2304]  (128x128, BK32)
  gemm_bt<1, 4, 4, 32><<<dim3(32, 18), 256, 0, stream>>>(xn, wqkvT, 768, 768, 2304, qkv, nullptr, nullptr, nullptr);

  // causal flash attention, split-KV x2 -> partials -> ctx [B,T,C]
  attn_kernel<<<1536, 256, 0, stream>>>(q, k, vt, po, olp);
  attn_combine<<<3072, 256, 0, stream>>>(po, olp, ctx);

  // x_a = ctx @ Wo + bo + x   (fp32, 128x64 BK64 dbuf, 384 blocks)
  gemm_bt<3, 4, 2, 64><<<dim3(32, 12), 256, 0, stream>>>(ctx, woT, 768, 768, 768, nullptr, xa, bo, x);

  // LN2 (xn2/olp dead after combine; p0 written only at proj -- safe)
  ln_kernel<<<4096, 256, 0, stream>>>(xa, g2, be2, xn2);

  // h = gelu(xn2 @ W_fc + b_fc)   (bf16, 128x128 BK32)
  gemm_bt<4, 4, 4, 32><<<dim3(32, 24), 256, 0, stream>>>(xn2, wfcT, 768, 768, 3072, hbuf, nullptr, b_fc, nullptr);

  // proj split-K=2: z=0 -> pK, z=1 -> pK + 4096*768 (= qkv region)
  gemm_bt<6, 4, 2, 64><<<dim3(32, 12, 2), 256, 0, stream>>>(hbuf, wprT, 1536, 3072, 768, nullptr, pK, nullptr, nullptr);

  // out = p0 + p1 + b_proj + xa
  redk_kernel<<<1024, 256, 0, stream>>>(pK, pK + (size_t)4096 * 768, b_proj, xa, out);
}

// Round 20
// 168.938 us; speedup vs baseline: 1.1006x; 1.0060x over previous
//
#include <hip/hip_runtime.h>
#include <hip/hip_bf16.h>

#define B_  2
#define T_  2048
#define C_  768
#define H_  12
#define HD_ 64

// scores are computed in exp2 domain: Q is pre-scaled by 0.125*log2(e)
#define QSCALE 0.18033688011f

typedef short bf16x8 __attribute__((ext_vector_type(8)));
typedef float f32x4  __attribute__((ext_vector_type(4)));
typedef unsigned short u16;
typedef unsigned int u32;

__device__ __forceinline__ u16 f2b(float f) {
  __hip_bfloat16 h = __float2bfloat16(f);
  return __builtin_bit_cast(u16, h);
}

// cheap round-half-up float->bf16 (no NaN handling; 2 VALU ops)
__device__ __forceinline__ u16 f2b_fast(float f) {
  u32 u = __builtin_bit_cast(u32, f);
  return (u16)((u + 0x8000u) >> 16);
}

__device__ __forceinline__ float b2f(u16 v) {
  u32 u = (u32)v << 16;
  return __builtin_bit_cast(float, u);
}

// pack two floats to bf16 pair in one u32: 2 adds + 1 v_perm_b32
__device__ __forceinline__ u32 pack2(float a, float b) {
  u32 ua = __builtin_bit_cast(u32, a) + 0x8000u;
  u32 ub = __builtin_bit_cast(u32, b) + 0x8000u;
  return __builtin_amdgcn_perm(ub, ua, 0x07060302);
}

__device__ __forceinline__ void gload_lds16(const u16* g, u16* l) {
  __builtin_amdgcn_global_load_lds(
      (__attribute__((address_space(1))) void*)(void*)g,
      (__attribute__((address_space(3))) void*)(void*)l,
      16, 0, 0);
}

// ---------------- LayerNorm body: fp32 in -> bf16 out ----------------
__device__ __forceinline__ void ln_body(const float* __restrict__ x,
                                        const float* __restrict__ g,
                                        const float* __restrict__ b,
                                        u16* __restrict__ out, int row) {
  int tid = threadIdx.x;
  const float* xr = x + (size_t)row * C_;
  float v0 = xr[tid], v1 = xr[tid + 256], v2 = xr[tid + 512];
  float s = v0 + v1 + v2;
  float q = v0 * v0 + v1 * v1 + v2 * v2;
  for (int m = 1; m < 64; m <<= 1) {
    s += __shfl_xor(s, m, 64);
    q += __shfl_xor(q, m, 64);
  }
  __shared__ float red[8];
  int wv = tid >> 6, ln = tid & 63;
  if (ln == 0) { red[wv] = s; red[4 + wv] = q; }
  __syncthreads();
  s = red[0] + red[1] + red[2] + red[3];
  q = red[4] + red[5] + red[6] + red[7];
  float mu  = s * (1.0f / C_);
  float var = q * (1.0f / C_) - mu * mu;
  float rs  = rsqrtf(var + 1e-5f);
  u16* orow = out + (size_t)row * C_;
  orow[tid]       = f2b(g[tid]       * (v0 - mu) * rs + b[tid]);
  orow[tid + 256] = f2b(g[tid + 256] * (v1 - mu) * rs + b[tid + 256]);
  orow[tid + 512] = f2b(g[tid + 512] * (v2 - mu) * rs + b[tid + 512]);
}

__global__ __launch_bounds__(256) void ln_kernel(const float* __restrict__ x,
                                                 const float* __restrict__ g,
                                                 const float* __restrict__ b,
                                                 u16* __restrict__ out) {
  ln_body(x, g, b, out, blockIdx.x);
}

// ------------- transpose+convert: fp32 W[K,N] -> bf16 Bt[N,K] -------------
__device__ __forceinline__ void tcvt_body(const float* __restrict__ W,
                                          u16* __restrict__ Bt,
                                          int Kd, int Nd, int bx, int by) {
  __shared__ u16 tile[32][33];
  int j0 = bx * 32, i0 = by * 32;
  int tx = threadIdx.x & 31, ty = threadIdx.x >> 5;  // ty 0..7
#pragma unroll
  for (int p = 0; p < 4; p++)
    tile[p * 8 + ty][tx] = f2b(W[(size_t)(i0 + p * 8 + ty) * Nd + j0 + tx]);
  __syncthreads();
#pragma unroll
  for (int p = 0; p < 4; p++)
    Bt[(size_t)(j0 + p * 8 + ty) * Kd + i0 + tx] = tile[tx][p * 8 + ty];
}

// ------- merged prologue: LN1 (blocks 0..4095) + all weight tcvt -------
__global__ __launch_bounds__(256) void prologue_kernel(
    const float* __restrict__ x, const float* __restrict__ g1,
    const float* __restrict__ be1, u16* __restrict__ xn,
    const float* __restrict__ Wq, const float* __restrict__ Wk,
    const float* __restrict__ Wv, const float* __restrict__ Wo,
    const float* __restrict__ Wfc, const float* __restrict__ Wpr,
    u16* __restrict__ Oq, u16* __restrict__ Ok, u16* __restrict__ Ov,
    u16* __restrict__ Oo, u16* __restrict__ Ofc, u16* __restrict__ Opr) {
  int id = blockIdx.x;
  if (id < 4096) {
    ln_body(x, g1, be1, xn, id);
    return;
  }
  id -= 4096;
  if (id < 2304) {                       // four 768x768, 576 tiles each
    int w = id / 576, idx = id - w * 576;
    const float* W = (w == 0) ? Wq : (w == 1) ? Wk : (w == 2) ? Wv : Wo;
    u16* O = (w == 0) ? Oq : (w == 1) ? Ok : (w == 2) ? Ov : Oo;
    tcvt_body(W, O, 768, 768, idx % 24, idx / 24);
  } else if (id < 4608) {                // W_fc [768,3072]
    int idx = id - 2304;
    tcvt_body(Wfc, Ofc, 768, 3072, idx % 96, idx / 96);
  } else {                               // W_proj [3072,768]
    int idx = id - 4608;
    tcvt_body(Wpr, Opr, 3072, 768, idx % 24, idx / 24);
  }
}

// ------------- GEMM: C[M,N] = A[M,K](bf16) * Bt[N,K]^T(bf16) -------------
// (MR*32) x (NR*32) tile, template BK, double-buffered LDS, ONE barrier per
// K-step. XOR-swizzled LDS (inverse-swizzled global source, swizzled reads).
// Swizzle: BK64 rows (128B): ch ^= row&7.  BK32 rows (64B): ch ^= (row>>1)&3.
// K = loop extent; lda = row stride of A and Bt (differs for split-K).
// MODE 1: fused QKV epilogue: q pre-scaled [B,H,T,64]; k [B,H,T,64];
//         v^T [B,H,64,T] with kv-within-64 permutation pi (for attn reg-P).
// MODE 3/5: fp32 acc+bias+resid   4: bf16 gelu(acc+bias)
// MODE 6: split-K partial, z = K-half; z==0 folds bias+resid; raw fp32.
template <int MODE, int MR, int NR, int BK>
__global__ __launch_bounds__(256) void gemm_bt(const u16* __restrict__ A,
                                               const u16* __restrict__ Bt,
                                               int K, int lda, int N,
                                               u16* __restrict__ outB,
                                               float* __restrict__ outF,
                                               const float* __restrict__ bias,
                                               const float* __restrict__ resid) {
  constexpr int BM = MR * 32;
  constexpr int BN = NR * 32;
  constexpr int CH = BK / 8;       // 16B chunks per row
  constexpr int KK = BK / 32;      // K slices per step
  __shared__ u16 As[2][BM * BK];
  __shared__ u16 Bs[2][BN * BK];
  int tid = threadIdx.x;
  int wave = tid >> 6, lane = tid & 63;
  int wr = wave >> 1, wc = wave & 1;
  int laneQ = lane >> 4, laneM = lane & 15;
  int bm = blockIdx.x * BM, bn = blockIdx.y * BN;
  int zofs = (MODE == 6) ? blockIdx.z * K : 0;   // K-half offset (split-K)

  auto rsw = [](int row) {
    return (CH == 4) ? ((row >> 1) & 3) : (row & (CH - 1));
  };

  f32x4 zero = {0.f, 0.f, 0.f, 0.f};
  f32x4 acc[MR][NR];
#pragma unroll
  for (int m = 0; m < MR; m++)
#pragma unroll
    for (int n = 0; n < NR; n++) acc[m][n] = zero;

  auto stage = [&](int buf, int k0) {
#pragma unroll
    for (int i = 0; i < (BM * CH) / 256; i++) {
      int c = i * 256 + tid;
      int row = c / CH, sw = (c % CH) ^ rsw(row);
      gload_lds16(A + (size_t)(bm + row) * lda + zofs + k0 + (sw << 3),
                  &As[buf][(size_t)(i * 256 + wave * 64) * 8]);
    }
#pragma unroll
    for (int i = 0; i < (BN * CH) / 256; i++) {
      int c = i * 256 + tid;
      int row = c / CH, sw = (c % CH) ^ rsw(row);
      gload_lds16(Bt + (size_t)(bn + row) * lda + zofs + k0 + (sw << 3),
                  &Bs[buf][(size_t)(i * 256 + wave * 64) * 8]);
    }
  };

  auto compute = [&](int buf) {
    const u16* Ab = As[buf];
    const u16* Bb = Bs[buf];
#pragma unroll
    for (int kk = 0; kk < KK; kk++) {
      bf16x8 af[MR], bfr[NR];
#pragma unroll
      for (int m = 0; m < MR; m++) {
        int row = wr * (MR * 16) + m * 16 + laneM;
        int ch = (((kk << 2) | laneQ) & (CH - 1)) ^ rsw(row);
        af[m] = *(const bf16x8*)(Ab + row * BK + (ch << 3));
      }
#pragma unroll
      for (int n = 0; n < NR; n++) {
        int row = wc * (NR * 16) + n * 16 + laneM;
        int ch = (((kk << 2) | laneQ) & (CH - 1)) ^ rsw(row);
        bfr[n] = *(const bf16x8*)(Bb + row * BK + (ch << 3));
      }
      __builtin_amdgcn_s_setprio(1);
#pragma unroll
      for (int m = 0; m < MR; m++)
#pragma unroll
        for (int n = 0; n < NR; n++)
          acc[m][n] = __builtin_amdgcn_mfma_f32_16x16x32_bf16(af[m], bfr[n],
                                                              acc[m][n], 0, 0, 0);
      __builtin_amdgcn_s_setprio(0);
    }
  };

  int nk = K / BK;
  stage(0, 0);
  for (int t = 0; t < nk; ++t) {
    int cur = t & 1;
    __syncthreads();               // stage(t) landed in all waves
    if (t + 1 < nk) stage(cur ^ 1, (t + 1) * BK);
    compute(cur);
  }

  u16* kout  = outB + (size_t)4096 * 768;
  u16* vtout = outB + (size_t)2 * 4096 * 768;
  float* zoutF = (MODE == 6) ? outF + (size_t)blockIdx.z * 4096 * 768 : outF;
#pragma unroll
  for (int m = 0; m < MR; m++) {
#pragma unroll
    for (int n = 0; n < NR; n++) {
#pragma unroll
      for (int r = 0; r < 4; r++) {
        int row = bm + wr * (MR * 16) + m * 16 + laneQ * 4 + r;
        int col = bn + wc * NR * 16 + n * 16 + laneM;
        float v = acc[m][n][r];
        if (MODE == 1) {
          int b = row >> 11, t = row & 2047;
          int which = col / 768;
          int cc = col - which * 768;
          int h = cc >> 6, d = cc & 63;
          if (which == 0)
            outB[(((size_t)(b * H_ + h)) * T_ + t) * HD_ + d] = f2b(v * QSCALE);
          else if (which == 1)
            kout[(((size_t)(b * H_ + h)) * T_ + t) * HD_ + d] = f2b(v);
          else {
            // permute kv-within-64: kv=16*t4+4*Qb+rb -> k'=32*(t4>>1)+8*Qb+4*(t4&1)+rb
            int tt = t & 63;
            int t4 = tt >> 4, Qb = (tt >> 2) & 3, rb = tt & 3;
            int kp = ((t4 >> 1) << 5) | (Qb << 3) | ((t4 & 1) << 2) | rb;
            vtout[(((size_t)(b * H_ + h)) * HD_ + d) * T_ + (t & ~63) + kp] = f2b(v);
          }
        } else if (MODE == 3 || MODE == 5) {
          outF[(size_t)row * N + col] = v + bias[col] + resid[(size_t)row * N + col];
        } else if (MODE == 4) {
          float u = v + bias[col];
          outB[(size_t)row * N + col] = f2b(0.5f * u * (1.0f + erff(u * 0.70710678118f)));
        } else if (MODE == 6) {
          float add = (blockIdx.z == 0)
                        ? bias[col] + resid[(size_t)row * N + col] : 0.f;
          zoutF[(size_t)row * N + col] = v + add;
        }
      }
    }
  }
}

// ------------- split-K reduce: out = p0 + p1 (bias/resid pre-folded) ------
__global__ __launch_bounds__(256) void redk_kernel(const float* __restrict__ p0,
                                                   const float* __restrict__ p1,
                                                   float* __restrict__ out) {
  const int n4 = 4096 * 768 / 4;
  for (int i = blockIdx.x * 256 + threadIdx.x; i < n4; i += gridDim.x * 256) {
    f32x4 a = ((const f32x4*)p0)[i];
    f32x4 b = ((const f32x4*)p1)[i];
    ((f32x4*)out)[i] = a + b;
  }
}

// ------- flash attention, split-KV x2, register-resident P, KVBLK=64 ------
// Q (pre-scaled by 0.125*log2e), K: [B*H, T, 64] bf16. Vt: [B*H, 64, T] bf16
// with kv-within-64 permutation pi applied at the QKV epilogue.
// Swapped QK^T (mfma(K,Q)); MAX-FREE softmax (implicit max 0 shared by all
// parts -> partial o/ol over disjoint kv ranges combine by ADDITION).
// Grid 1536: id = (ii<<1)|z; part z covers kv tiles [z?ks:0, z?n:ks).
// Partials: po[z][B,T,C] BF16 (o bounded ~5e4, bf16-safe), olp[z][bh][T] f32.
// 4 waves x 16 q-rows; 2-buffer LDS 32KB -> 5 blocks/CU.
__global__ __launch_bounds__(256) void attn_kernel(const u16* __restrict__ Q,
                                                   const u16* __restrict__ K,
                                                   const u16* __restrict__ Vt,
                                                   u16* __restrict__ po,
                                                   float* __restrict__ olp) {
  __shared__ u16 Ks[2][4096];
  __shared__ u16 Vs[2][4096];

  int tid = threadIdx.x;
  int wave = tid >> 6, lane = tid & 63;
  int laneQ = lane >> 4, laneM = lane & 15;
  int id = blockIdx.x;
  int ii = id >> 1, z = id & 1;
  int bh = ii % 24;
  int bx = 31 - ii / 24;          // LPT: longest parts first
  int n  = bx + 1;
  int ks = (n + 1) >> 1;
  int kb0  = z ? ks : 0;
  int kEnd = z ? n  : ks;
  int q0 = bx * 64 + wave * 16;
  int qrel = wave * 16 + laneM;   // causal threshold within the diagonal tile

  const u16* Qb = Q  + ((size_t)bh * T_ + q0) * HD_;
  const u16* Kb = K  + (size_t)bh * T_ * HD_;
  const u16* Vb = Vt + (size_t)bh * HD_ * T_;

  bf16x8 qf[2];
  qf[0] = *(const bf16x8*)(Qb + laneM * HD_ + laneQ * 8);
  qf[1] = *(const bf16x8*)(Qb + laneM * HD_ + 32 + laneQ * 8);

  bf16x8 onesf;
#pragma unroll
  for (int i = 0; i < 8; i++) onesf[i] = (short)0x3F80;  // bf16 1.0

  f32x4 zero = {0.f, 0.f, 0.f, 0.f};
  f32x4 o[4];
  f32x4 ol = zero;                 // row-sums (D-layout, q = 4*laneQ+r)
#pragma unroll
  for (int g = 0; g < 4; g++) o[g] = zero;

  auto stage = [&](int buf, int kb) {
    const u16* Kt = Kb + (size_t)kb * 64 * HD_;  // contiguous 64x64 tile
#pragma unroll
    for (int h = 0; h < 2; h++) {
      int c = h * 256 + wave * 64 + lane;
      int row = c >> 3, c8 = c & 7;
      int sw = c8 ^ (row & 7);
      gload_lds16(Kt + (size_t)((row << 3) | sw) * 8,
                  &Ks[buf][(size_t)(h * 256 + wave * 64) * 8]);
      gload_lds16(Vb + (size_t)row * T_ + kb * 64 + (sw << 3),
                  &Vs[buf][(size_t)(h * 256 + wave * 64) * 8]);
    }
  };

  if (kb0 < kEnd) stage(0, kb0);
  for (int kb = kb0; kb < kEnd; ++kb) {
    int cur = (kb - kb0) & 1;
    __syncthreads();  // staged 'cur' landed (vmcnt0) across all waves
    if (kb + 1 < kEnd) stage(cur ^ 1, kb + 1);
    const u16* Ksb = Ks[cur];
    const u16* Vsb = Vs[cur];

    // --- QK^T swapped: s[t][r] = score(kv = 16t+4laneQ+r, q = laneM) ---
    f32x4 s[4];
#pragma unroll
    for (int t = 0; t < 4; t++) s[t] = zero;
    __builtin_amdgcn_s_setprio(1);
#pragma unroll
    for (int t = 0; t < 4; t++) {
      int krow = t * 16 + laneM;
#pragma unroll
      for (int c = 0; c < 2; c++) {
        bf16x8 kf = *(const bf16x8*)(Ksb + krow * 64 +
                                     ((((c << 2) | laneQ) ^ (krow & 7)) << 3));
        s[t] = __builtin_amdgcn_mfma_f32_16x16x32_bf16(kf, qf[c], s[t], 0, 0, 0);
      }
    }
    __builtin_amdgcn_s_setprio(0);

    // causal mask (diagonal tile only): exp2(-1e30) == 0
    if (kb == bx) {
#pragma unroll
      for (int t = 0; t < 4; t++)
#pragma unroll
        for (int r = 0; r < 4; r++)
          if (16 * t + 4 * laneQ + r > qrel) s[t][r] = -1e30f;
    }

    // --- P = exp2(s) directly (max-free), packed to bf16 in registers ---
    union { u32 u[4]; bf16x8 v; } P0, P1;
#pragma unroll
    for (int t = 0; t < 2; t++) {
      P0.u[2 * t]     = pack2(exp2f(s[t][0]), exp2f(s[t][1]));
      P0.u[2 * t + 1] = pack2(exp2f(s[t][2]), exp2f(s[t][3]));
      P1.u[2 * t]     = pack2(exp2f(s[t + 2][0]), exp2f(s[t + 2][1]));
      P1.u[2 * t + 1] = pack2(exp2f(s[t + 2][2]), exp2f(s[t + 2][3]));
    }

    // --- PV: o += P * V  (+ ones-column row-sum) ---
    __builtin_amdgcn_s_setprio(1);
#pragma unroll
    for (int g = 0; g < 4; g++) {
      int d = g * 16 + laneM;
      bf16x8 v0 = *(const bf16x8*)(Vsb + d * 64 + ((laneQ ^ (d & 7)) << 3));
      bf16x8 v1 = *(const bf16x8*)(Vsb + d * 64 + (((4 | laneQ) ^ (d & 7)) << 3));
      o[g] = __builtin_amdgcn_mfma_f32_16x16x32_bf16(P0.v, v0, o[g], 0, 0, 0);
      o[g] = __builtin_amdgcn_mfma_f32_16x16x32_bf16(P1.v, v1, o[g], 0, 0, 0);
    }
    ol = __builtin_amdgcn_mfma_f32_16x16x32_bf16(P0.v, onesf, ol, 0, 0, 0);
    ol = __builtin_amdgcn_mfma_f32_16x16x32_bf16(P1.v, onesf, ol, 0, 0, 0);
    __builtin_amdgcn_s_setprio(0);
  }

  // write bf16 partials (empty parts write zeros)
  int b = bh / H_, h = bh % H_;
  u16* poz = po + (size_t)z * 4096 * 768;
#pragma unroll
  for (int r = 0; r < 4; r++) {
    int t = q0 + laneQ * 4 + r;
    size_t base = ((size_t)(b * T_ + t)) * C_ + h * HD_;
#pragma unroll
    for (int g = 0; g < 4; g++)
      poz[base + g * 16 + laneM] = f2b_fast(o[g][r]);
    if (laneM == 0)
      olp[(size_t)(z * 24 + bh) * T_ + t] = ol[r];
  }
}

// ------- combine: ctx = (o0+o1) / (ol0+ol1), bf16 partials in, bf16 out ----
__global__ __launch_bounds__(256) void attn_combine(const u16* __restrict__ po,
                                                    const float* __restrict__ olp,
                                                    u16* __restrict__ ctx) {
  int i = blockIdx.x * 256 + threadIdx.x;   // [0, 4096*768/4)
  const ushort4* p0 = (const ushort4*)po;
  const ushort4* p1 = (const ushort4*)(po + (size_t)4096 * 768);
  ushort4 a = p0[i], c4 = p1[i];
  int idx = i << 2;
  int row = idx / 768;
  int cc = idx - row * 768;
  int h = cc >> 6;
  int b = row >> 11, t = row & 2047;
  int bh = b * H_ + h;
  float l = olp[(size_t)bh * T_ + t] + olp[(size_t)(24 + bh) * T_ + t];
  float inv = 1.0f / l;
  u32 lo = pack2((b2f(a.x) + b2f(c4.x)) * inv, (b2f(a.y) + b2f(c4.y)) * inv);
  u32 hi = pack2((b2f(a.z) + b2f(c4.z)) * inv, (b2f(a.w) + b2f(c4.w)) * inv);
  u32* dst = (u32*)(ctx + (size_t)idx);
  dst[0] = lo;
  dst[1] = hi;
}

// ---------------------------------------------------------------
extern "C" void kernel_launch(void* const* d_in, const int* in_sizes, int n_in,
                              void* d_out, int out_size, void* d_ws, size_t ws_size,
                              hipStream_t stream) {
  const float* x      = (const float*)d_in[0];
  const float* Wq     = (const float*)d_in[1];
  const float* Wk     = (const float*)d_in[2];
  const float* Wv     = (const float*)d_in[3];
  const float* Wo     = (const float*)d_in[4];
  const float* bo     = (const float*)d_in[5];
  const float* W_fc   = (const float*)d_in[6];
  const float* b_fc   = (const float*)d_in[7];
  const float* W_proj = (const float*)d_in[8];
  const float* b_proj = (const float*)d_in[9];
  const float* g1     = (const float*)d_in[10];
  const float* be1    = (const float*)d_in[11];
  const float* g2     = (const float*)d_in[12];
  const float* be2    = (const float*)d_in[13];
  float* out = (float*)d_out;

  char* ws = (char*)d_ws;
  size_t off = 0;
  auto alloc = [&](size_t bytes) {
    size_t o = off;
    off += (bytes + 255) & ~(size_t)255;
    return o;
  };
  u16*   xn    = (u16*)(ws + alloc((size_t)4096 * 768 * 2));
  u16*   xn2   = (u16*)(ws + alloc((size_t)4096 * 768 * 2));
  u16*   qkv   = (u16*)(ws + alloc((size_t)3 * 4096 * 768 * 2));
  u16*   ctx   = (u16*)(ws + alloc((size_t)4096 * 768 * 2));
  float* xa    = (float*)(ws + alloc((size_t)4096 * 768 * 4));
  u16*   hbuf  = (u16*)(ws + alloc((size_t)4096 * 3072 * 2));
  u16*   wqkvT = (u16*)(ws + alloc((size_t)2304 * 768 * 2));
  u16*   woT   = (u16*)(ws + alloc((size_t)768 * 768 * 2));
  u16*   wfcT  = (u16*)(ws + alloc((size_t)768 * 3072 * 2));
  u16*   wprT  = (u16*)(ws + alloc((size_t)3072 * 768 * 2));

  u16* q  = qkv;
  u16* k  = qkv + (size_t)4096 * 768;
  u16* vt = qkv + (size_t)2 * 4096 * 768;
  // split-K partials: p0 spans xn+xn2 (two contiguous 6.29MB allocs =
  // exactly 4096*768*4 B); p1 = pK + 4096*768 floats = start of qkv.
  float* pK = (float*)xn;
  // attn split-KV partials: po = hbuf region (2 x [4096][768] bf16 =
  // 12.6MB <= 25.2MB); olp = xn2 region (2 x 24 x 2048 fp32 = 384KB).
  // Both consumed by attn_combine before their next writers (FC / LN2).
  u16*   po  = hbuf;
  float* olp = (float*)xn2;

  // LN1 + all weight converts merged into ONE launch
  prologue_kernel<<<11008, 256, 0, stream>>>(
      x, g1, be1, xn,
      Wq, Wk, Wv, Wo, W_fc, W_proj,
      wqkvT, wqkvT + (size_t)768 * 768, wqkvT + (size_t)2 * 768 * 768,
      woT, wfcT, wprT);

  // fused QKV projection: [4096,768] @ [768,2304]  (128x128, BK32)
  gemm_bt<1, 4, 4, 32><<<dim3(32, 18), 256, 0, stream>>>(xn, wqkvT, 768, 768, 2304, qkv, nullptr, nullptr, nullptr);

  // causal flash attention, split-KV x2 -> bf16 partials -> ctx [B,T,C]
  attn_kernel<<<1536, 256, 0, stream>>>(q, k, vt, po, olp);
  attn_combine<<<3072, 256, 0, stream>>>(po, olp, ctx);

  // x_a = ctx @ Wo + bo + x   (fp32, 128x64 BK64 dbuf, 384 blocks)
  gemm_bt<3, 4, 2, 64><<<dim3(32, 12), 256, 0, stream>>>(ctx, woT, 768, 768, 768, nullptr, xa, bo, x);

  // LN2 (xn2/olp dead after combine; p0 written only at proj -- safe)
  ln_kernel<<<4096, 256, 0, stream>>>(xa, g2, be2, xn2);

  // h = gelu(xn2 @ W_fc + b_fc)   (bf16, 128x128 BK32)
  gemm_bt<4, 4, 4, 32><<<dim3(32, 24), 256, 0, stream>>>(xn2, wfcT, 768, 768, 3072, hbuf, nullptr, b_fc, nullptr);

  // proj split-K=2: z=0 -> pK (+bias+xa folded), z=1 -> pK + 4096*768 (qkv)
  gemm_bt<6, 4, 2, 64><<<dim3(32, 12, 2), 256, 0, stream>>>(hbuf, wprT, 1536, 3072, 768, nullptr, pK, b_proj, xa);

  // out = p0 + p1
  redk_kernel<<<1024, 256, 0, stream>>>(pK, pK + (size_t)4096 * 768, out);
}